// Round 2
// baseline (436.241 us; speedup 1.0000x reference)
//
#include <hip/hip_runtime.h>
#include <hip/hip_bf16.h>

// B=2, S=4096, E=1024 attention + QKV projections, all-fp16 MFMA pipeline:
//   cvt_mask  fp32->fp16 q,k,v,W* + mask -> 2MB bitmask (in d_out head)
//   gemm512   z=2: q/k projections, 256x256 tile, 512 thr, 8-phase core
//   gemm256   v^T projection (A=Wv, B=xv -> vt[b][e][s]), 256x128 4-phase core
//   gemm_qk   256x256 tile, 8-phase core, XCD-remapped: S'=exp(qk^T-3) masked
//   gemm_pv   256x128 tile, 4-phase core, K=4096: O = (S' vt) / l
//
// Swizzle note (round-2 fix): slots have 64B rows (32 f16). Bank of a
// b128 read = 16*(row&1) + 4*g. Using g = quad ^ ((row>>1)&3) makes each
// 16-lane group cover all 8 bank-groups twice (2-way = free); the old
// g = quad ^ (row&3) collapsed to 4 groups -> 4-way conflict (6.3M measured).

typedef _Float16 f16_t;
typedef _Float16 f16x8 __attribute__((ext_vector_type(8)));
typedef float f32x4 __attribute__((ext_vector_type(4)));
typedef unsigned long long u64;
typedef unsigned int uint;

union PackH8 { f16x8 v; f16_t e[8]; };

__device__ __forceinline__ f32x4 mfma_f16(f16x8 a, f16x8 b, f32x4 c) {
  return __builtin_amdgcn_mfma_f32_16x16x32_f16(a, b, c, 0, 0, 0);
}

__device__ __forceinline__ void cp16(const f16_t* g, f16_t* l) {
  __builtin_amdgcn_global_load_lds(
      (const __attribute__((address_space(1))) unsigned int*)g,
      (__attribute__((address_space(3))) unsigned int*)l, 16, 0, 0);
}

// ---- fp32 -> fp16 bulk convert (y=0..5) + mask bitpack (y=6) ----
__global__ __launch_bounds__(256) void cvt_mask(
    const float* __restrict__ q, const float* __restrict__ k,
    const float* __restrict__ v, const float* __restrict__ wq,
    const float* __restrict__ wk, const float* __restrict__ wv,
    const int* __restrict__ mask,
    f16_t* __restrict__ xq, f16_t* __restrict__ xk, f16_t* __restrict__ xv,
    f16_t* __restrict__ wqh, f16_t* __restrict__ wkh, f16_t* __restrict__ wvh,
    u64* __restrict__ mb) {
  if (blockIdx.y == 6) {
    const int lane = threadIdx.x & 63;
    int wid = blockIdx.x * 4 + (threadIdx.x >> 6);
    for (int w = wid; w < 262144; w += 16384) {
      const int pred = mask[(size_t)w * 64 + lane] != 0;
      u64 b = __ballot(pred);
      if (lane == 0) mb[w] = b;
    }
    return;
  }
  const float* src; f16_t* dst; size_t n;
  switch (blockIdx.y) {
    case 0: src = q;  dst = xq;  n = 8388608; break;
    case 1: src = k;  dst = xk;  n = 8388608; break;
    case 2: src = v;  dst = xv;  n = 8388608; break;
    case 3: src = wq; dst = wqh; n = 1048576; break;
    case 4: src = wk; dst = wkh; n = 1048576; break;
    default: src = wv; dst = wvh; n = 1048576; break;
  }
  size_t i = ((size_t)blockIdx.x * 256 + threadIdx.x) * 8;
  if (i >= n) return;
  float4 a = *(const float4*)(src + i);
  float4 b = *(const float4*)(src + i + 4);
  PackH8 p;
  p.e[0] = (f16_t)a.x; p.e[1] = (f16_t)a.y; p.e[2] = (f16_t)a.z; p.e[3] = (f16_t)a.w;
  p.e[4] = (f16_t)b.x; p.e[5] = (f16_t)b.y; p.e[6] = (f16_t)b.z; p.e[7] = (f16_t)b.w;
  *(f16x8*)(dst + i) = p.v;
}

#define TK 64

// ---- 8-phase pipelined 256x256 GEMM core (512 thr, 4Mx2N waves) -----------
// Ring of 4 half-K slots (256 rows x 32 k, 16KB) per matrix; 2 K-tiles/iter.
// Reads: phase p reads slot p>>1, quadrant p&1. Stages: p0:A->sl3 p1:B->sl3
// p2:A->sl0 p3:B->sl0+VM4 p4:A->sl1 p5:B->sl1 p6:A->sl2 p7:B->sl2+VM4.
// FIFO ledger (2 loads/unit): entering iter O={p6',p7'}=4; p3-end O=12,
// VM4 confirms sl2(p6',p7') for p4 read and sl3(p0,p1) for p6 read; p7-end
// O=12, VM4 confirms sl0(p2,p3)/sl1(p4,p5) for next iter. WAR: each slot
// restaged >=2 barriers after its last read. Last iter peeled: only the sl3
// stage is live (kb=K-32); VM0 at its p3 confirms sl2+sl3; no dead fetch.
__device__ __forceinline__ void core8ph(
    const f16_t* __restrict__ Ab, const f16_t* __restrict__ Bb,
    int m0, int n0, int K, int iters, f32x4 (&acc)[4][8]) {
  __shared__ f16_t lA[32768];
  __shared__ f16_t lB[32768];

  const int tid = threadIdx.x;
  const int w = tid >> 6, lane = tid & 63;
  const int quad = lane >> 4, l15 = lane & 15;
  const int wm = w >> 1, wn = w & 1;
  const int srow = lane >> 2;                     // staging: 4 lanes per row
  const int sg = (lane & 3) ^ ((lane >> 3) & 3);  // physical slot ^ f(row)

  const uint aoff0 = (uint)(m0 + w * 32 + srow) * K + sg * 8;
  const uint aoff1 = aoff0 + 16 * K;
  const uint boff0 = (uint)(n0 + w * 32 + srow) * K + sg * 8;
  const uint boff1 = boff0 + 16 * K;
  const int ld0 = (w * 32) * 32;
  const int ld1 = (w * 32 + 16) * 32;

  // read: logical k-group 'quad' of row r lives at physical quad^((r>>1)&3);
  // r == l15 (mod 16) and row-blocks are 16-aligned -> (r>>1)&3 == (l15>>1)&3
  int afo[4], bfo[8];
  const int swz = (quad ^ ((l15 >> 1) & 3)) * 8;
#pragma unroll
  for (int mi = 0; mi < 4; mi++) afo[mi] = (wm * 64 + mi * 16 + l15) * 32 + swz;
#pragma unroll
  for (int ni = 0; ni < 8; ni++) bfo[ni] = (wn * 128 + ni * 16 + l15) * 32 + swz;

#define STG_A(sl, kb) { cp16(Ab + aoff0 + (kb), lA + (sl) * 8192 + ld0); \
                        cp16(Ab + aoff1 + (kb), lA + (sl) * 8192 + ld1); }
#define STG_B(sl, kb) { cp16(Bb + boff0 + (kb), lB + (sl) * 8192 + ld0); \
                        cp16(Bb + boff1 + (kb), lB + (sl) * 8192 + ld1); }

  // prologue: sl0 = tile0 kh0, sl1 = tile0 kh1, sl2 = tile1 kh0
  STG_A(0, 0) STG_B(0, 0)
  STG_A(1, 32) STG_B(1, 32)
  STG_A(2, 64) STG_B(2, 64)
  asm volatile("s_waitcnt vmcnt(4)" ::: "memory");  // sl0,sl1 landed
  __builtin_amdgcn_s_barrier();

  f16x8 af[4], bf[8];

#define PH(SL, Q, STG, VMW) { \
    if ((Q) == 0) { \
      _Pragma("unroll") for (int mi = 0; mi < 4; mi++) \
        af[mi] = *(const f16x8*)(lA + (SL) * 8192 + afo[mi]); \
      _Pragma("unroll") for (int ni = 0; ni < 4; ni++) \
        bf[ni] = *(const f16x8*)(lB + (SL) * 8192 + bfo[ni]); \
    } else { \
      _Pragma("unroll") for (int ni = 4; ni < 8; ni++) \
        bf[ni] = *(const f16x8*)(lB + (SL) * 8192 + bfo[ni]); \
    } \
    STG \
    asm volatile("" ::: "memory"); \
    __builtin_amdgcn_s_barrier(); \
    asm volatile("s_waitcnt lgkmcnt(0)" ::: "memory"); \
    __builtin_amdgcn_sched_barrier(0); \
    __builtin_amdgcn_s_setprio(1); \
    _Pragma("unroll") for (int mi = 0; mi < 4; mi++) { \
      _Pragma("unroll") for (int nj = 0; nj < 4; nj++) { \
        const int ni = (Q) * 4 + nj; \
        acc[mi][ni] = mfma_f16(af[mi], bf[ni], acc[mi][ni]); \
      } } \
    __builtin_amdgcn_sched_barrier(0); \
    __builtin_amdgcn_s_setprio(0); \
    VMW \
    asm volatile("" ::: "memory"); \
    __builtin_amdgcn_s_barrier(); \
  }

#define VM4 asm volatile("s_waitcnt vmcnt(4)" ::: "memory");
#define VM0 asm volatile("s_waitcnt vmcnt(0)" ::: "memory");

  for (int i = 0; i < iters - 1; i++) {
    const int t0 = 2 * i;
    const int kb3 = (t0 + 1) * 64 + 32;
    const int kb0 = (t0 + 2) * 64;
    const int kb1 = kb0 + 32;
    const int kb2 = (t0 + 3) * 64;
    PH(0, 0, STG_A(3, kb3), )
    PH(0, 1, STG_B(3, kb3), )
    PH(1, 0, STG_A(0, kb0), )
    PH(1, 1, STG_B(0, kb0), VM4)
    PH(2, 0, STG_A(1, kb1), )
    PH(2, 1, STG_B(1, kb1), )
    PH(3, 0, STG_A(2, kb2), )
    PH(3, 1, STG_B(2, kb2), VM4)
  }
  {  // peeled last iteration: only sl3 stage is live
    const int kbp = K - 32;
    PH(0, 0, STG_A(3, kbp), )
    PH(0, 1, STG_B(3, kbp), )
    PH(1, 0, , )
    PH(1, 1, , VM0)
    PH(2, 0, , )
    PH(2, 1, , )
    PH(3, 0, , )
    PH(3, 1, , )
  }
#undef PH
#undef STG_A
#undef STG_B
}

// ---- 4-phase pipelined 256x128 GEMM core (512 thr, 4Mx2N waves) -----------
// Ring of 4 half-K slots: A 256x32 (16KB, 2 cp16), B 128x32 (8KB, 1 cp16);
// 2 K-tiles/iter, phase p reads slot p (tile 2i+(p>>1), kh p&1), 16 MFMA.
// Stages (3 loads/unit): p0->sl3 (tile 2i+1 kh1, read p3), p1->sl0,
// p2->sl1, p3->sl2 (next iter). VM6 at every phase-end confirms the stage
// from 2 phases ago, exactly one phase before its read. WAR: each slot is
// restaged one barrier after its read phase. Peeled last iter: p0 stage
// live (kb=K-32); VM6/VM3/VM0 drain the ledger in order.
__device__ __forceinline__ void core4ph(
    const f16_t* __restrict__ Ab, const f16_t* __restrict__ Bb,
    int m0, int n0, int K, int iters, f32x4 (&acc)[4][4]) {
  __shared__ f16_t lA[32768];   // 4 x 256x32
  __shared__ f16_t lB[16384];   // 4 x 128x32

  const int tid = threadIdx.x;
  const int w = tid >> 6, lane = tid & 63;
  const int quad = lane >> 4, l15 = lane & 15;
  const int wm = w >> 1, wn = w & 1;
  const int sg = (lane & 3) ^ ((lane >> 3) & 3);

  const uint arow = (uint)(w * 16 + (lane >> 2));
  const uint aoff0 = (uint)(m0 + arow) * K + sg * 8;
  const uint aoff1 = aoff0 + 128 * K;
  const uint boff  = (uint)(n0 + arow) * K + sg * 8;
  const int ldw = w * 512;   // wave-uniform LDS elem offset (lane*8 added by HW)

  int afo[4], bfo[4];
  const int swz = (quad ^ ((l15 >> 1) & 3)) * 8;
#pragma unroll
  for (int mi = 0; mi < 4; mi++) afo[mi] = (wm * 64 + mi * 16 + l15) * 32 + swz;
#pragma unroll
  for (int ni = 0; ni < 4; ni++) bfo[ni] = (wn * 64 + ni * 16 + l15) * 32 + swz;

#define STG4(sl, kb) { cp16(Ab + aoff0 + (kb), lA + (sl) * 8192 + ldw); \
                       cp16(Ab + aoff1 + (kb), lA + (sl) * 8192 + 4096 + ldw); \
                       cp16(Bb + boff  + (kb), lB + (sl) * 4096 + ldw); }

  STG4(0, 0)
  STG4(1, 32)
  STG4(2, 64)
  asm volatile("s_waitcnt vmcnt(3)" ::: "memory");  // sl0,sl1 landed
  __builtin_amdgcn_s_barrier();

  f16x8 af[4], bf[4];

#define PH4(SL, STG, VMW) { \
    _Pragma("unroll") for (int mi = 0; mi < 4; mi++) \
      af[mi] = *(const f16x8*)(lA + (SL) * 8192 + afo[mi]); \
    _Pragma("unroll") for (int ni = 0; ni < 4; ni++) \
      bf[ni] = *(const f16x8*)(lB + (SL) * 4096 + bfo[ni]); \
    STG \
    asm volatile("" ::: "memory"); \
    __builtin_amdgcn_s_barrier(); \
    asm volatile("s_waitcnt lgkmcnt(0)" ::: "memory"); \
    __builtin_amdgcn_sched_barrier(0); \
    __builtin_amdgcn_s_setprio(1); \
    _Pragma("unroll") for (int mi = 0; mi < 4; mi++) { \
      _Pragma("unroll") for (int ni = 0; ni < 4; ni++) { \
        acc[mi][ni] = mfma_f16(af[mi], bf[ni], acc[mi][ni]); \
      } } \
    __builtin_amdgcn_sched_barrier(0); \
    __builtin_amdgcn_s_setprio(0); \
    VMW \
    asm volatile("" ::: "memory"); \
    __builtin_amdgcn_s_barrier(); \
  }

#define VM6 asm volatile("s_waitcnt vmcnt(6)" ::: "memory");
#define VM3 asm volatile("s_waitcnt vmcnt(3)" ::: "memory");

  for (int i = 0; i < iters - 1; i++) {
    const int t0 = 2 * i;
    PH4(0, STG4(3, (t0 + 1) * 64 + 32), VM6)
    PH4(1, STG4(0, (t0 + 2) * 64), VM6)
    PH4(2, STG4(1, (t0 + 2) * 64 + 32), VM6)
    PH4(3, STG4(2, (t0 + 3) * 64), VM6)
  }
  {  // peeled last iteration: only the sl3 stage is live
    PH4(0, STG4(3, K - 32), VM6)
    PH4(1, , VM3)
    PH4(2, , VM0)
    PH4(3, , )
  }
#undef PH4
#undef STG4
#undef VM6
#undef VM3
#undef VM4
#undef VM0
}

// ---- 256x256-tile projection GEMM: C = (A B^T + bias) * scale ----
__global__ __launch_bounds__(512, 2) void gemm512(
    const f16_t* __restrict__ A, const f16_t* __restrict__ B,
    f16_t* __restrict__ C, const float* __restrict__ bias0,
    const float* __restrict__ bias1, int K,
    long sAz, long sBz, long sCz, float scale0, float scale1, int Cstride) {
  const int bz = blockIdx.z;
  const int n0 = blockIdx.x * 256;
  const int m0 = blockIdx.y * 256;
  const f16_t* Ab = A + (size_t)sAz * bz;
  const f16_t* Bb = B + (size_t)sBz * bz;

  f32x4 acc[4][8] = {};
  core8ph(Ab, Bb, m0, n0, K, K >> 7, acc);

  const int tid = threadIdx.x;
  const int w = tid >> 6, lane = tid & 63;
  const int quad = lane >> 4, l15 = lane & 15;
  const int wm = w >> 1, wn = w & 1;
  const float* bias = bz ? bias1 : bias0;
  const float scale = bz ? scale1 : scale0;
  f16_t* Cb = C + (size_t)sCz * bz;
#pragma unroll
  for (int mi = 0; mi < 4; mi++) {
#pragma unroll
    for (int ni = 0; ni < 8; ni++) {
      const int gm0 = m0 + wm * 64 + mi * 16 + quad * 4;
      const int gn = n0 + wn * 128 + ni * 16 + l15;
#pragma unroll
      for (int r = 0; r < 4; r++) {
        const int gm = gm0 + r;
        Cb[(size_t)gm * Cstride + gn] = (f16_t)((acc[mi][ni][r] + bias[gn]) * scale);
      }
    }
  }
}

// ---- v^T projection, 256x128 4-phase core: C[gn>>12][gm][gn&4095] ----
__global__ __launch_bounds__(512, 2) void gemm256(
    const f16_t* __restrict__ A, const f16_t* __restrict__ B,
    f16_t* __restrict__ C, const float* __restrict__ bias0, int K) {
  const int n0 = blockIdx.x * 128;
  const int m0 = blockIdx.y * 256;

  f32x4 acc[4][4] = {};
  core4ph(A, B, m0, n0, K, K >> 7, acc);

  const int tid = threadIdx.x;
  const int w = tid >> 6, lane = tid & 63;
  const int quad = lane >> 4, l15 = lane & 15;
  const int wm = w >> 1, wn = w & 1;
#pragma unroll
  for (int mi = 0; mi < 4; mi++) {
#pragma unroll
    for (int ni = 0; ni < 4; ni++) {
      const int gm0 = m0 + wm * 64 + mi * 16 + quad * 4;
      const int gn = n0 + wn * 64 + ni * 16 + l15;
#pragma unroll
      for (int r = 0; r < 4; r++) {
        const int gm = gm0 + r;
        const int bb = gn >> 12;
        const int s = gn & 4095;
        C[(size_t)bb * 4194304 + (size_t)gm * 4096 + s] =
            (f16_t)(acc[mi][ni][r] + bias0[gm]);
      }
    }
  }
}

// ---- QK^T 256x256, 8-phase core, XCD-remapped + constant-max softmax ----
__global__ __launch_bounds__(512, 2) void gemm_qk(
    const f16_t* __restrict__ A, const f16_t* __restrict__ B,
    f16_t* __restrict__ S, const u64* __restrict__ mb,
    float* __restrict__ lrow) {
  // bijective XCD remap: each XCD owns 2 m-tiles x 16 n-tiles x 2 bz
  // -> A panels (2MB) resident in its 4MB L2.
  const int bid = blockIdx.x;
  const int xcd = bid & 7;
  const int l = bid >> 3;
  const int bz = l >> 5;
  const int r5 = l & 31;
  const int m0 = (xcd * 2 + (r5 >> 4)) * 256;
  const int n0 = (r5 & 15) * 256;
  const f16_t* Ab = A + (size_t)4194304 * bz;
  const f16_t* Bb = B + (size_t)4194304 * bz;

  f32x4 acc[4][8] = {};
  core8ph(Ab, Bb, m0, n0, 1024, 8, acc);

  // epilogue: p = exp(s-3) masked (bitmask), store f16, row sums -> atomicAdd
  const int tid = threadIdx.x;
  const int w = tid >> 6, lane = tid & 63;
  const int quad = lane >> 4, l15 = lane & 15;
  const int wm = w >> 1, wn = w & 1;
  f16_t* Sb = S + (size_t)16777216 * bz;
  float* lb = lrow + bz * 4096;
  const int wbase = (n0 >> 6) + wn * 2;
#pragma unroll
  for (int mi = 0; mi < 4; mi++) {
#pragma unroll
    for (int r = 0; r < 4; r++) {
      const int gm = m0 + wm * 64 + mi * 16 + quad * 4 + r;
      const u64 w0 = mb[(size_t)gm * 64 + wbase];
      const u64 w1 = mb[(size_t)gm * 64 + wbase + 1];
      float rs = 0.f;
#pragma unroll
      for (int ni = 0; ni < 8; ni++) {
        const int col_l = ni * 16 + l15;
        const u64 mw = (ni < 4) ? w0 : w1;
        const int bit = (int)((mw >> (col_l & 63)) & 1);
        const float p = bit ? 0.f : __expf(acc[mi][ni][r] - 3.0f);
        Sb[(size_t)gm * 4096 + n0 + wn * 128 + col_l] = (f16_t)p;
        rs += p;
      }
      rs += __shfl_xor(rs, 1); rs += __shfl_xor(rs, 2);
      rs += __shfl_xor(rs, 4); rs += __shfl_xor(rs, 8);
      if (l15 == 0) atomicAdd(&lb[gm], rs);
    }
  }
}

// ---- PV GEMM 256x128, K=4096, 4-phase core, XCD-remapped: O=(S' vt)/l ----
__global__ __launch_bounds__(512, 2) void gemm_pv(
    const f16_t* __restrict__ S, const f16_t* __restrict__ V,
    float* __restrict__ O, const float* __restrict__ lrow) {
  const int bid = blockIdx.x;          // 256 blocks = 1/CU
  const int xcd = bid & 7;
  const int l = bid >> 3;
  const int bz = l >> 4;
  const int r4 = l & 15;
  const int m0 = (xcd * 2 + (r4 >> 3)) * 256;
  const int n0 = (r4 & 7) * 128;

  const f16_t* Ab = S + (size_t)16777216 * bz;
  const f16_t* Bb = V + (size_t)4194304 * bz;

  f32x4 acc[4][4] = {};
  core4ph(Ab, Bb, m0, n0, 4096, 32, acc);

  const int tid = threadIdx.x;
  const int w = tid >> 6, lane = tid & 63;
  const int quad = lane >> 4, l15 = lane & 15;
  const int wm = w >> 1, wn = w & 1;
  float* Ob = O + (size_t)4194304 * bz;
  const float* lb = lrow + bz * 4096;
#pragma unroll
  for (int mi = 0; mi < 4; mi++) {
#pragma unroll
    for (int ni = 0; ni < 4; ni++) {
      const int gm0 = m0 + wm * 64 + mi * 16 + quad * 4;
      const int gn = n0 + wn * 64 + ni * 16 + l15;
#pragma unroll
      for (int r = 0; r < 4; r++) {
        const int gm = gm0 + r;
        Ob[(size_t)gm * 1024 + gn] = acc[mi][ni][r] * (1.0f / lb[gm]);
      }
    }
  }
}

// ======================= launch =======================
extern "C" void kernel_launch(void* const* d_in, const int* in_sizes, int n_in,
                              void* d_out, int out_size, void* d_ws, size_t ws_size,
                              hipStream_t stream) {
  const float* query = (const float*)d_in[0];
  const float* key_  = (const float*)d_in[1];
  const float* value = (const float*)d_in[2];
  const int* mask    = (const int*)d_in[3];
  const float* Wq = (const float*)d_in[4];
  const float* bq = (const float*)d_in[5];
  const float* Wk = (const float*)d_in[6];
  const float* bk = (const float*)d_in[7];
  const float* Wv = (const float*)d_in[8];
  const float* bv = (const float*)d_in[9];
  float* out = (float*)d_out;

  const size_t MB = (size_t)1 << 20;
  char* w = (char*)d_ws;
  f16_t* qb  = (f16_t*)(w);
  f16_t* kb  = (f16_t*)(w + 16 * MB);
  f16_t* vt  = (f16_t*)(w + 32 * MB);
  f16_t* xq  = (f16_t*)(w + 48 * MB);
  f16_t* xk  = (f16_t*)(w + 64 * MB);
  f16_t* xv  = (f16_t*)(w + 80 * MB);
  f16_t* wqh = (f16_t*)(w + 96 * MB);
  f16_t* wkh = (f16_t*)(w + 98 * MB);
  f16_t* wvh = (f16_t*)(w + 100 * MB);
  f16_t* S   = (f16_t*)(w + 48 * MB);   // overlaps x/W after projections
  float* ls  = (float*)(w + 112 * MB);
  u64* mb = (u64*)d_out;                 // dead until PV writes out

  cvt_mask<<<dim3(4096, 7), 256, 0, stream>>>(query, key_, value, Wq, Wk, Wv,
                                              mask, xq, xk, xv, wqh, wkh, wvh, mb);
  // q & k projections fused (z=2), 256x256 tile: q scaled by 1/32 (exact pow2)
  gemm512<<<dim3(4, 32, 2), 512, 0, stream>>>(
      xq, wqh, qb, bq, bk, 1024, 8388608L, 1048576L, 8388608L,
      0.03125f, 1.0f, 1024);
  // v^T: A=Wv [1024xK], B=xv [8192xK] -> vt[b][e][s]
  gemm256<<<dim3(64, 4), 512, 0, stream>>>(wvh, xv, vt, bv, 1024);
  hipMemsetAsync(ls, 0, 2 * 4096 * sizeof(float), stream);
  // S' = exp(qk^T - 3) masked, l row sums
  gemm_qk<<<dim3(512), 512, 0, stream>>>(qb, kb, S, mb, ls);
  // O = S' vt / l
  gemm_pv<<<dim3(256), 512, 0, stream>>>(S, vt, out, ls);
}